// Round 16
// baseline (104.967 us; speedup 1.0000x reference)
//
#include <hip/hip_runtime.h>
#include <hip/hip_bf16.h>

#define NB 16
#define QL 1024
#define DLEN 4096
#define HD 128

#define KCB 128               // k columns per block
#define NKC (DLEN / KCB)      // 32 k-chunk blocks per batch
#define NIT (QL / 32)         // 32 intervals of 32 q rows

typedef __attribute__((ext_vector_type(8))) short short8;
typedef __attribute__((ext_vector_type(4))) short short4v;
typedef __attribute__((ext_vector_type(4))) float f32x4;

__device__ __forceinline__ short bf16_of(float x) {
  union { __hip_bfloat16 h; short s; } u;
  u.h = __float2bfloat16(x);
  return u.s;
}
__device__ __forceinline__ float f32_of_bf16(short s) {
  union { unsigned u; float f; } v;
  v.u = ((unsigned)(unsigned short)s) << 16;
  return v.f;
}
__device__ __forceinline__ short8 cvt8(float4 a, float4 b) {
  short8 r;
  r[0] = bf16_of(a.x); r[1] = bf16_of(a.y); r[2] = bf16_of(a.z); r[3] = bf16_of(a.w);
  r[4] = bf16_of(b.x); r[5] = bf16_of(b.y); r[6] = bf16_of(b.z); r[7] = bf16_of(b.w);
  return r;
}

// Pre-pass: Q fp32 -> bf16 (4.2 MB), once.
__global__ __launch_bounds__(256) void cvt_q(const float* __restrict__ in,
                                             short8* __restrict__ outw) {
  const size_t i = (size_t)blockIdx.x * 256 + threadIdx.x;
  const float* p = in + i * 8;
  outw[i] = cvt8(*(const float4*)p, *(const float4*)(p + 4));
}

// Round 16: producer/consumer WAVE SPECIALIZATION. R12-R15: four schedules,
// same ~88us -- every wave mixed streaming with MFMA/exp/reduce chains, so
// the sim stream kept getting gated behind compute. Now: block=(b, 128-k
// chunk), 4 producer waves (doc A-frags fixed in regs; stream Q; P=exp(QK^T)
// masked -> bf16 into LDS ping-pong) + 4 consumer waves whose ONLY vmem is
// the sim stream (wave-private 2-deep global_load_lds rings, counted
// vmcnt(4/5), never drained; vmcnt is per-wave so compute chains in OTHER
// waves cannot couple to it). One raw s_barrier per interval flips P.
// Sim LDS layout == read order (j*1024+lane*16 -> conflict-free b128);
// P bf16 XOR-swizzled ((row&7)<<4). No-max softmax as before (exact 0 for
// masked via predication; scores ~N(0,1) cannot overflow).
__global__ __launch_bounds__(512, 4) void atten_cross(
    const __hip_bfloat16* __restrict__ qbf, const float* __restrict__ doc,
    const int* __restrict__ dmask, const float* __restrict__ sim,
    float2* __restrict__ ws) {
  const int flat = blockIdx.x;
  const int b = flat & 15;        // flat%8 == b%8 -> batch pinned to one XCD
  const int kc = flat >> 4;       // 0..31: this block's 128-k chunk
  const int tid = threadIdx.x;
  const int w = tid >> 6;         // 0..3 producers, 4..7 consumers
  const int lane = tid & 63;

  __shared__ char lds[6 * 8192];  // [0,32K): 4 consumer rings; [32K,48K): P dbuf
  constexpr float scale = 0.088388347648318447f;  // 1/sqrt(128)

  if (w < 4) {
    // ================= PRODUCER =================
    const int qh = w & 1;         // q half (16 rows of the 32-row interval)
    const int kq = w >> 1;        // k half (64 of the 128 k)
    const int grp = lane >> 4, li = lane & 15;

    // doc A-frags (fixed): k rows kc*128 + kq*64 + t*16 + li, d chunk cc
    const float* dsrc = doc + ((size_t)b * DLEN + kc * KCB + kq * 64 + li) * HD + grp * 8;
    short8 afr[4][4];
#pragma unroll
    for (int t = 0; t < 4; ++t)
#pragma unroll
      for (int cc = 0; cc < 4; ++cc) {
        const float* p = dsrc + (size_t)t * 16 * HD + cc * 32;
        afr[t][cc] = cvt8(*(const float4*)p, *(const float4*)(p + 4));
      }
    // mask bits for owned k positions
    int mm[4][4];
    {
      const int* mp = dmask + (size_t)b * DLEN + kc * KCB + kq * 64 + grp * 4;
#pragma unroll
      for (int t = 0; t < 4; ++t) {
        const int4 m = *(const int4*)(mp + t * 16);
        mm[t][0] = m.x; mm[t][1] = m.y; mm[t][2] = m.z; mm[t][3] = m.w;
      }
    }
    // P write offsets (bf16, row-major 256B/row, XOR-swizzled)
    const int prow = qh * 16 + li;
    const int swz = (prow & 7) << 4;
    int pwo[4];
#pragma unroll
    for (int t = 0; t < 4; ++t)
      pwo[t] = (prow * 256 + kq * 128 + t * 32 + grp * 8) ^ swz;
    // Q source (bf16): row qh*16+li (+32/interval), d chunk grp*8 + cc*32
    const char* gq = (const char*)qbf +
                     (((size_t)b * QL + qh * 16 + li) * HD + grp * 8) * 2;

#define COMPUTE_P(itq, pbase)                                                  \
    {                                                                          \
      const char* qp_ = gq + (size_t)(itq) * (32 * HD * 2);                    \
      short8 bq[4];                                                            \
      _Pragma("unroll") for (int cc = 0; cc < 4; ++cc)                         \
        bq[cc] = *(const short8*)(qp_ + cc * 64);                              \
      _Pragma("unroll") for (int t = 0; t < 4; ++t) {                          \
        f32x4 acc = {0.f, 0.f, 0.f, 0.f};                                      \
        _Pragma("unroll") for (int cc = 0; cc < 4; ++cc)                       \
          acc = __builtin_amdgcn_mfma_f32_16x16x32_bf16(afr[t][cc], bq[cc],    \
                                                        acc, 0, 0, 0);         \
        short4v pv;                                                            \
        _Pragma("unroll") for (int r = 0; r < 4; ++r) {                        \
          float e = __expf(acc[r] * scale);                                    \
          pv[r] = bf16_of(mm[t][r] ? e : 0.f); /* == exp(-9999) == 0 */        \
        }                                                                      \
        *(short4v*)((pbase) + pwo[t]) = pv;                                    \
      }                                                                        \
    }

    COMPUTE_P(0, lds + 32768);                       // P(0) -> buf0
    asm volatile("s_waitcnt lgkmcnt(0)" ::: "memory");
#pragma unroll 1
    for (int it = 0; it < NIT; ++it) {
      __builtin_amdgcn_s_barrier();                  // publish P(it)
      asm volatile("" ::: "memory");
      if (it + 1 < NIT) {
        COMPUTE_P(it + 1, lds + 32768 + ((it + 1) & 1) * 8192);
      }
      asm volatile("s_waitcnt lgkmcnt(0)" ::: "memory");
    }
#undef COMPUTE_P
  } else {
    // ================= CONSUMER =================
    const int cw = w - 4;          // 0..3: q-row octet within the 32-row interval
    const int r8 = lane >> 3, c8 = lane & 7;
    char* ring = lds + cw * 8192;  // private 2 x 4KB
    const int prow = cw * 8 + r8;
    const int pswz = (prow & 7) << 4;
    int ppo[4];
#pragma unroll
    for (int j = 0; j < 4; ++j)
      ppo[j] = (prow * 256 + (c8 * 16 + j * 4) * 2) ^ pswz;

    // sim global src per j: row (it*32 + prow), cols kc*128 + c8*16 + j*4 (+..4)
    const char* gs[4];
#pragma unroll
    for (int j = 0; j < 4; ++j)
      gs[j] = (const char*)sim +
              (((size_t)b * QL + prow) * DLEN + kc * KCB + c8 * 16 + j * 4) * 4;

#define STAGE(itq, bsel)                                                       \
    {                                                                          \
      const size_t adv = (size_t)(itq) * (32 * DLEN * 4);                      \
      _Pragma("unroll") for (int j = 0; j < 4; ++j)                            \
        __builtin_amdgcn_global_load_lds(                                      \
            (const __attribute__((address_space(1))) void*)(gs[j] + adv),      \
            (__attribute__((address_space(3))) void*)(ring + (bsel) * 4096 +   \
                                                      j * 1024 + lane * 16),   \
            16, 0, 0);                                                         \
    }

    STAGE(0, 0);
#pragma unroll 1
    for (int it = 0; it < NIT; ++it) {
      __builtin_amdgcn_s_barrier();                  // P(it) visible
      asm volatile("" ::: "memory");
      {  // stage it+1 into buf (it+1)&1 (this wave consumed it at it-1)
        const int nx = (it + 1 < NIT) ? it + 1 : NIT - 1;  // tail: dead reload
        STAGE(nx, (it + 1) & 1);
      }
      // wait for stage(it): newer = stage(it+1)[4] (+ store(it-1) when it>=1)
      if (it == 0) asm volatile("s_waitcnt vmcnt(4)" ::: "memory");
      else         asm volatile("s_waitcnt vmcnt(5)" ::: "memory");
      __builtin_amdgcn_sched_barrier(0);

      const char* sb = ring + (it & 1) * 4096;
      const char* pb = lds + 32768 + (it & 1) * 8192;
      float l = 0.f, n = 0.f;
#pragma unroll
      for (int j = 0; j < 4; ++j) {
        const f32x4 sv = *(const f32x4*)(sb + j * 1024 + lane * 16);
        const short4v pv = *(const short4v*)(pb + ppo[j]);
#pragma unroll
        for (int r = 0; r < 4; ++r) {
          const float p = f32_of_bf16(pv[r]);
          l += p;
          n = fmaf(p, sv[r], n);
        }
      }
      // reduce across the 8 lanes (c8) sharing this q-row
      l += __shfl_xor(l, 1, 64); l += __shfl_xor(l, 2, 64); l += __shfl_xor(l, 4, 64);
      n += __shfl_xor(n, 1, 64); n += __shfl_xor(n, 2, 64); n += __shfl_xor(n, 4, 64);
      if (c8 == 0)
        ws[((size_t)kc * NB + b) * QL + it * 32 + prow] = make_float2(l, n);
    }
#undef STAGE
  }
}

// Finish: per (b,q) sum the 32 k-chunk partials, v=n/l, sum over q -> out[b].
// 256 blocks x 256 threads, coalesced; one atomicAdd per block.
__global__ __launch_bounds__(256) void finish(const float2* __restrict__ ws,
                                              float* __restrict__ out) {
  const int b = blockIdx.x;
  const int qg = blockIdx.y;
  const int t = threadIdx.x;
  const int q = qg * 64 + (t & 63);
  const int sg = t >> 6;  // wave id: 8 k-chunks each

  float l = 0.f, n = 0.f;
#pragma unroll
  for (int s = sg * 8; s < sg * 8 + 8; ++s) {
    const float2 v = ws[((size_t)s * NB + b) * QL + q];
    l += v.x;
    n += v.y;
  }
  __shared__ float rl[4][64], rn[4][64];
  rl[sg][t & 63] = l;
  rn[sg][t & 63] = n;
  __syncthreads();
  if (t < 64) {
    const float lt = rl[0][t] + rl[1][t] + rl[2][t] + rl[3][t];
    const float nt = rn[0][t] + rn[1][t] + rn[2][t] + rn[3][t];
    float v = nt / lt;
#pragma unroll
    for (int m = 32; m >= 1; m >>= 1) v += __shfl_xor(v, m, 64);
    if (t == 0) atomicAdd(out + b, v);
  }
}

extern "C" void kernel_launch(void* const* d_in, const int* in_sizes, int n_in,
                              void* d_out, int out_size, void* d_ws, size_t ws_size,
                              hipStream_t stream) {
  const float* qin = (const float*)d_in[0];
  // d_in[1] = query_mask: unused by the reference
  const float* doc = (const float*)d_in[2];
  const int* dmask = (const int*)d_in[3];
  const float* sim = (const float*)d_in[4];
  float* out = (float*)d_out;

  // ws layout: [0, 4 MB) = (l,n) partials (32*16*1024 float2); [4 MB, +4.2 MB) = Q bf16
  float2* ws = (float2*)d_ws;
  short8* qbf = (short8*)((char*)d_ws + (size_t)NKC * NB * QL * 8);

  hipMemsetAsync(out, 0, (size_t)out_size * sizeof(float), stream);

  const size_t q_elems = (size_t)NB * QL * HD;  // 2.1M floats
  cvt_q<<<q_elems / (8 * 256), 256, 0, stream>>>(qin, qbf);

  dim3 grid(NB * NKC);  // 512 blocks: flat = kc*16 + b (2 per CU)
  atten_cross<<<grid, 512, 0, stream>>>((const __hip_bfloat16*)qbf, doc,
                                        dmask, sim, ws);
  finish<<<dim3(NB, 16), 256, 0, stream>>>(ws, out);
}